// Round 6
// baseline (2350.674 us; speedup 1.0000x reference)
//
#include <hip/hip_runtime.h>
#include <hip/hip_bf16.h>
#include <math.h>

#define TPTS 96
#define CTOT 128
#define LDP 134   // LDS row pitch u16: <=2-way banks for b128 reads/b64 writes (verified R4)

typedef __bf16 bf16x8_t __attribute__((ext_vector_type(8)));
typedef float f32x4_t __attribute__((ext_vector_type(4)));
typedef unsigned short us8_t __attribute__((ext_vector_type(8)));

__device__ __forceinline__ unsigned short f2b(float f) {
    union { float f; unsigned int i; } v; v.f = f;
    unsigned int r = v.i + 0x7fffu + ((v.i >> 16) & 1u);
    return (unsigned short)(r >> 16);
}
__device__ __forceinline__ unsigned int packbf2(float a, float b) {
#if __has_builtin(__builtin_amdgcn_cvt_pk_bf16_f32)
    typedef __bf16 bf16x2_t __attribute__((ext_vector_type(2)));
    bf16x2_t v = __builtin_amdgcn_cvt_pk_bf16_f32(a, b);
    return __builtin_bit_cast(unsigned int, v);
#else
    return (unsigned int)f2b(a) | ((unsigned int)f2b(b) << 16);
#endif
}
__device__ __forceinline__ uint2 pack4(float v0, float v1, float v2, float v3) {
    uint2 w; w.x = packbf2(v0, v1); w.y = packbf2(v2, v3); return w;
}
__device__ __forceinline__ float u2f_lo(unsigned int w) {
    union { unsigned int i; float f; } v; v.i = w << 16; return v.f;
}
__device__ __forceinline__ float u2f_hi(unsigned int w) {
    union { unsigned int i; float f; } v; v.i = w & 0xffff0000u; return v.f;
}
__device__ __forceinline__ f32x4_t mfma16(bf16x8_t a, bf16x8_t b, f32x4_t c) {
    return __builtin_amdgcn_mfma_f32_16x16x32_bf16(a, b, c, 0, 0, 0);
}
__device__ __forceinline__ bf16x8_t ldfrag(const unsigned short* p) {
    us8_t v = *(const us8_t*)p;
    return __builtin_bit_cast(bf16x8_t, v);
}
__device__ __forceinline__ bf16x8_t ldfragW(const float* p) {
    float4 a = *(const float4*)p;
    float4 b = *(const float4*)(p + 4);
    bf16x8_t r;
    r[0] = __builtin_bit_cast(__bf16, f2b(a.x)); r[1] = __builtin_bit_cast(__bf16, f2b(a.y));
    r[2] = __builtin_bit_cast(__bf16, f2b(a.z)); r[3] = __builtin_bit_cast(__bf16, f2b(a.w));
    r[4] = __builtin_bit_cast(__bf16, f2b(b.x)); r[5] = __builtin_bit_cast(__bf16, f2b(b.y));
    r[6] = __builtin_bit_cast(__bf16, f2b(b.z)); r[7] = __builtin_bit_cast(__bf16, f2b(b.w));
    return r;
}
__device__ __forceinline__ float tanh2(float x) {   // finite inputs only
    float e = __expf(x + x);
    return 1.f - __fdividef(2.f, e + 1.f);
}
__device__ __forceinline__ float sigm(float x) {
    return __fdividef(1.f, 1.f + __expf(-x));
}

// ============ K1: ODE, dual row-group per block (32 blocks x 32 rows) =========
// Transposed MFMA: D = Wode * z^T; C-layout feat=quad*4+i, col(batch row)=l15.
// Groups A (rows rbase..+15) and B (+16..+31) share weights; their independent
// read->mfma->tanh->update chains fill each other's post-barrier stall.
__global__ void __launch_bounds__(512, 1)
k_ode(const float* __restrict__ yl, const float* __restrict__ yh,
      const float* __restrict__ Wode, const float* __restrict__ bode,
      unsigned short* __restrict__ yTraj)
{
    const int tid = threadIdx.x, lane = tid & 63, wv = tid >> 6;
    const int l15 = lane & 15, quad = lane >> 4;
    const int fbase = wv * 16 + quad * 4;
    const int rbase = blockIdx.x * 32;

    __shared__ __align__(16) unsigned short zbuf[2][32][LDP];

    bf16x8_t wode[4];
#pragma unroll
    for (int kt = 0; kt < 4; ++kt)
        wode[kt] = ldfragW(Wode + (wv * 16 + l15) * CTOT + kt * 32 + quad * 8);
    float bo[4];
    {
        float4 b4 = *(const float4*)(bode + fbase);
        bo[0] = b4.x; bo[1] = b4.y; bo[2] = b4.z; bo[3] = b4.w;
    }

    float yA[4], yB[4];
    {
        int rA = rbase + l15, rB = rbase + 16 + l15;
#pragma unroll
        for (int i = 0; i < 4; ++i) {
            int f = fbase + i;
            yA[i] = (f < 32) ? yl[rA * 32 + f] : yh[rA * 96 + (f - 32)];
            yB[i] = (f < 32) ? yl[rB * 32 + f] : yh[rB * 96 + (f - 32)];
        }
        *(uint2*)&zbuf[0][l15][fbase]      = pack4(yA[0], yA[1], yA[2], yA[3]);
        *(uint2*)&zbuf[0][16 + l15][fbase] = pack4(yB[0], yB[1], yB[2], yB[3]);
        *(uint2*)(yTraj + ((size_t)rA) * CTOT + fbase) = pack4(yA[0], yA[1], yA[2], yA[3]);
        *(uint2*)(yTraj + ((size_t)rB) * CTOT + fbase) = pack4(yB[0], yB[1], yB[2], yB[3]);
    }
    __syncthreads();

    const float dt = 1.0f / 95.0f;
    const float B1 = 35.f / 384.f, B3 = 500.f / 1113.f, B4 = 125.f / 192.f,
                B5 = -2187.f / 6784.f, B6 = 11.f / 84.f;

    int p = 0;
    float krA[6][4], krB[6][4];
#pragma unroll 1
    for (int t = 0; t < 95; ++t) {
#pragma unroll
        for (int s = 0; s < 6; ++s) {
            bf16x8_t fA[4], fB[4];
#pragma unroll
            for (int kt = 0; kt < 4; ++kt) {
                fA[kt] = ldfrag(&zbuf[p][l15][kt * 32 + quad * 8]);
                fB[kt] = ldfrag(&zbuf[p][16 + l15][kt * 32 + quad * 8]);
            }
            f32x4_t aA = {0.f, 0.f, 0.f, 0.f}, aB = {0.f, 0.f, 0.f, 0.f};
#pragma unroll
            for (int kt = 0; kt < 4; ++kt) {
                aA = mfma16(wode[kt], fA[kt], aA);
                aB = mfma16(wode[kt], fB[kt], aB);
            }
#pragma unroll
            for (int i = 0; i < 4; ++i) {
                krA[s][i] = tanh2(aA[i] + bo[i]);
                krB[s][i] = tanh2(aB[i] + bo[i]);
            }
            if (s < 5) {
                float zA[4], zB[4];
#pragma unroll
                for (int i = 0; i < 4; ++i) {
                    float zvA, zvB;
                    if (s == 0) {
                        zvA = 0.2f * krA[0][i]; zvB = 0.2f * krB[0][i];
                    } else if (s == 1) {
                        zvA = (3.f/40.f)*krA[0][i] + (9.f/40.f)*krA[1][i];
                        zvB = (3.f/40.f)*krB[0][i] + (9.f/40.f)*krB[1][i];
                    } else if (s == 2) {
                        zvA = (44.f/45.f)*krA[0][i] + (-56.f/15.f)*krA[1][i] + (32.f/9.f)*krA[2][i];
                        zvB = (44.f/45.f)*krB[0][i] + (-56.f/15.f)*krB[1][i] + (32.f/9.f)*krB[2][i];
                    } else if (s == 3) {
                        zvA = (19372.f/6561.f)*krA[0][i] + (-25360.f/2187.f)*krA[1][i]
                            + (64448.f/6561.f)*krA[2][i] + (-212.f/729.f)*krA[3][i];
                        zvB = (19372.f/6561.f)*krB[0][i] + (-25360.f/2187.f)*krB[1][i]
                            + (64448.f/6561.f)*krB[2][i] + (-212.f/729.f)*krB[3][i];
                    } else {
                        zvA = (9017.f/3168.f)*krA[0][i] + (-355.f/33.f)*krA[1][i]
                            + (46732.f/5247.f)*krA[2][i] + (49.f/176.f)*krA[3][i]
                            + (-5103.f/18656.f)*krA[4][i];
                        zvB = (9017.f/3168.f)*krB[0][i] + (-355.f/33.f)*krB[1][i]
                            + (46732.f/5247.f)*krB[2][i] + (49.f/176.f)*krB[3][i]
                            + (-5103.f/18656.f)*krB[4][i];
                    }
                    zA[i] = yA[i] + dt * zvA; zB[i] = yB[i] + dt * zvB;
                }
                *(uint2*)&zbuf[p ^ 1][l15][fbase]      = pack4(zA[0], zA[1], zA[2], zA[3]);
                *(uint2*)&zbuf[p ^ 1][16 + l15][fbase] = pack4(zB[0], zB[1], zB[2], zB[3]);
            } else {
#pragma unroll
                for (int i = 0; i < 4; ++i) {
                    yA[i] += dt * (B1*krA[0][i] + B3*krA[2][i] + B4*krA[3][i] + B5*krA[4][i] + B6*krA[5][i]);
                    yB[i] += dt * (B1*krB[0][i] + B3*krB[2][i] + B4*krB[3][i] + B5*krB[4][i] + B6*krB[5][i]);
                }
                uint2 pA = pack4(yA[0], yA[1], yA[2], yA[3]);
                uint2 pB = pack4(yB[0], yB[1], yB[2], yB[3]);
                *(uint2*)&zbuf[p ^ 1][l15][fbase]      = pA;
                *(uint2*)&zbuf[p ^ 1][16 + l15][fbase] = pB;
                *(uint2*)(yTraj + ((size_t)(t + 1) * 1024 + rbase + l15) * CTOT + fbase) = pA;
                *(uint2*)(yTraj + ((size_t)(t + 1) * 1024 + rbase + 16 + l15) * CTOT + fbase) = pB;
            }
            __syncthreads();
            p ^= 1;
        }
    }
}

// ============ K2/K4: bulk input-gate GEMM, full-GPU parallel ==================
// gi[t][rt][wv][g][lane] (uint2 = 4 bf16) = (Wih * src_t^T), no bias.
__global__ void __launch_bounds__(512, 1)
k_gates(const float* __restrict__ W, const unsigned short* __restrict__ src,
        uint2* __restrict__ gi)
{
    const int tid = threadIdx.x, lane = tid & 63, wv = tid >> 6;
    const int l15 = lane & 15, quad = lane >> 4;
    const int t = blockIdx.x >> 6, rt = blockIdx.x & 63;

    const unsigned short* xp = src + ((size_t)t * 1024 + rt * 16 + l15) * CTOT;
    bf16x8_t bf[4];
#pragma unroll
    for (int kt = 0; kt < 4; ++kt) bf[kt] = ldfrag(xp + kt * 32 + quad * 8);
#pragma unroll
    for (int g = 0; g < 3; ++g) {
        bf16x8_t wf[4];
#pragma unroll
        for (int kt = 0; kt < 4; ++kt)
            wf[kt] = ldfragW(W + (size_t)(g * 128 + wv * 16 + l15) * CTOT + kt * 32 + quad * 8);
        f32x4_t a = {0.f, 0.f, 0.f, 0.f};
#pragma unroll
        for (int kt = 0; kt < 4; ++kt) a = mfma16(wf[kt], bf[kt], a);
        gi[((size_t)(t * 64 + rt) * 24 + wv * 3 + g) * 64 + lane] = pack4(a[0], a[1], a[2], a[3]);
    }
}

// ============ K3/K5: GRU h-recurrence, dual row-group, gates precomputed ======
__global__ void __launch_bounds__(512, 1)
k_gru(const float* __restrict__ Whh, const float* __restrict__ bih, const float* __restrict__ bhh,
      const uint2* __restrict__ gi, unsigned short* __restrict__ outTraj,
      const float* __restrict__ W1v, const float* __restrict__ b1v,
      const float* __restrict__ W2v, const float* __restrict__ b2v,
      float* __restrict__ outp, int doHead)
{
    const int tid = threadIdx.x, lane = tid & 63, wv = tid >> 6;
    const int l15 = lane & 15, quad = lane >> 4;
    const int fbase = wv * 16 + quad * 4;
    const int rbase = blockIdx.x * 32;
    const int rtA = blockIdx.x * 2, rtB = rtA + 1;

    __shared__ __align__(16) unsigned short zbuf[2][32][LDP];
    __shared__ __align__(16) unsigned short hidbuf[32][72];

    bf16x8_t whh[3][4];
#pragma unroll
    for (int g = 0; g < 3; ++g)
#pragma unroll
        for (int kt = 0; kt < 4; ++kt)
            whh[g][kt] = ldfragW(Whh + (size_t)(g * 128 + wv * 16 + l15) * CTOT + kt * 32 + quad * 8);
    float bi[3][4], bh[3][4];
#pragma unroll
    for (int g = 0; g < 3; ++g) {
        float4 a = *(const float4*)(bih + g * 128 + fbase);
        float4 b = *(const float4*)(bhh + g * 128 + fbase);
        bi[g][0] = a.x; bi[g][1] = a.y; bi[g][2] = a.z; bi[g][3] = a.w;
        bh[g][0] = b.x; bh[g][1] = b.y; bh[g][2] = b.z; bh[g][3] = b.w;
    }

    float hA[4] = {0.f, 0.f, 0.f, 0.f}, hB[4] = {0.f, 0.f, 0.f, 0.f};
    *(uint2*)&zbuf[0][l15][fbase]      = pack4(0.f, 0.f, 0.f, 0.f);
    *(uint2*)&zbuf[0][16 + l15][fbase] = pack4(0.f, 0.f, 0.f, 0.f);
    __syncthreads();

#define GIX(t, rt, g) (((size_t)((t) * 64 + (rt)) * 24 + wv * 3 + (g)) * 64 + lane)
    uint2 a0[3], a1[3], a2[3], b0[3], b1[3], b2[3];
#pragma unroll
    for (int g = 0; g < 3; ++g) {
        a0[g] = gi[GIX(0, rtA, g)]; a1[g] = gi[GIX(1, rtA, g)];
        b0[g] = gi[GIX(0, rtB, g)]; b1[g] = gi[GIX(1, rtB, g)];
    }

    int p = 0;
#pragma unroll 1
    for (int t = 0; t < TPTS; ++t) {
        if (t + 2 < TPTS) {
#pragma unroll
            for (int g = 0; g < 3; ++g) {
                a2[g] = gi[GIX(t + 2, rtA, g)];
                b2[g] = gi[GIX(t + 2, rtB, g)];
            }
        }
        bf16x8_t fA[4], fB[4];
#pragma unroll
        for (int kt = 0; kt < 4; ++kt) {
            fA[kt] = ldfrag(&zbuf[p][l15][kt * 32 + quad * 8]);
            fB[kt] = ldfrag(&zbuf[p][16 + l15][kt * 32 + quad * 8]);
        }
        f32x4_t gA[3], gB[3];
#pragma unroll
        for (int g = 0; g < 3; ++g) {
            gA[g] = (f32x4_t){0.f, 0.f, 0.f, 0.f};
            gB[g] = (f32x4_t){0.f, 0.f, 0.f, 0.f};
        }
#pragma unroll
        for (int kt = 0; kt < 4; ++kt) {
            gA[0] = mfma16(whh[0][kt], fA[kt], gA[0]);
            gB[0] = mfma16(whh[0][kt], fB[kt], gB[0]);
            gA[1] = mfma16(whh[1][kt], fA[kt], gA[1]);
            gB[1] = mfma16(whh[1][kt], fB[kt], gB[1]);
            gA[2] = mfma16(whh[2][kt], fA[kt], gA[2]);
            gB[2] = mfma16(whh[2][kt], fB[kt], gB[2]);
        }
        float grA[3][4], grB[3][4];
#pragma unroll
        for (int g = 0; g < 3; ++g) {
            grA[g][0] = u2f_lo(a0[g].x); grA[g][1] = u2f_hi(a0[g].x);
            grA[g][2] = u2f_lo(a0[g].y); grA[g][3] = u2f_hi(a0[g].y);
            grB[g][0] = u2f_lo(b0[g].x); grB[g][1] = u2f_hi(b0[g].x);
            grB[g][2] = u2f_lo(b0[g].y); grB[g][3] = u2f_hi(b0[g].y);
        }
#pragma unroll
        for (int i = 0; i < 4; ++i) {
            float rA = sigm((grA[0][i] + bi[0][i]) + (gA[0][i] + bh[0][i]));
            float zA = sigm((grA[1][i] + bi[1][i]) + (gA[1][i] + bh[1][i]));
            float nA = tanh2((grA[2][i] + bi[2][i]) + rA * (gA[2][i] + bh[2][i]));
            hA[i] = (1.f - zA) * nA + zA * hA[i];
            float rB = sigm((grB[0][i] + bi[0][i]) + (gB[0][i] + bh[0][i]));
            float zB = sigm((grB[1][i] + bi[1][i]) + (gB[1][i] + bh[1][i]));
            float nB = tanh2((grB[2][i] + bi[2][i]) + rB * (gB[2][i] + bh[2][i]));
            hB[i] = (1.f - zB) * nB + zB * hB[i];
        }
        uint2 pA = pack4(hA[0], hA[1], hA[2], hA[3]);
        uint2 pB = pack4(hB[0], hB[1], hB[2], hB[3]);
        *(uint2*)&zbuf[p ^ 1][l15][fbase]      = pA;
        *(uint2*)&zbuf[p ^ 1][16 + l15][fbase] = pB;
        if (outTraj) {
            *(uint2*)(outTraj + ((size_t)t * 1024 + rbase + l15) * CTOT + fbase)      = pA;
            *(uint2*)(outTraj + ((size_t)t * 1024 + rbase + 16 + l15) * CTOT + fbase) = pB;
        }
        __syncthreads();
        p ^= 1;
#pragma unroll
        for (int g = 0; g < 3; ++g) { a0[g] = a1[g]; a1[g] = a2[g]; b0[g] = b1[g]; b1[g] = b2[g]; }
    }
#undef GIX

    if (doHead) {
        // hidden^T = gelu(W1 * h2^T): 4 m-tiles x 2 groups = 8 wave-jobs
        int grp = wv >> 2, mt = wv & 3;
        int lrow = grp * 16 + l15;
        bf16x8_t wf[4], hf[4];
#pragma unroll
        for (int kt = 0; kt < 4; ++kt) {
            wf[kt] = ldfragW(W1v + (size_t)(mt * 16 + l15) * CTOT + kt * 32 + quad * 8);
            hf[kt] = ldfrag(&zbuf[p][lrow][kt * 32 + quad * 8]);
        }
        f32x4_t acc = {0.f, 0.f, 0.f, 0.f};
#pragma unroll
        for (int kt = 0; kt < 4; ++kt) acc = mfma16(wf[kt], hf[kt], acc);
        float4 bb = *(const float4*)(b1v + mt * 16 + quad * 4);
        const float* bbp = (const float*)&bb;
        float gl[4];
#pragma unroll
        for (int i = 0; i < 4; ++i) {
            float x = acc[i] + bbp[i];
            gl[i] = 0.5f * x * (1.0f + erff(x * 0.70710678118654752f));
        }
        *(uint2*)&hidbuf[lrow][mt * 16 + quad * 4] = pack4(gl[0], gl[1], gl[2], gl[3]);
        __syncthreads();

        bf16x8_t hdA[2], hdB[2];
#pragma unroll
        for (int kt = 0; kt < 2; ++kt) {
            hdA[kt] = ldfrag(&hidbuf[l15][kt * 32 + quad * 8]);
            hdB[kt] = ldfrag(&hidbuf[16 + l15][kt * 32 + quad * 8]);
        }
#pragma unroll 1
        for (int j = 0; j < 24; ++j) {
            int mt2 = wv * 24 + j;
            bf16x8_t wf0 = ldfragW(W2v + (size_t)(mt2 * 16 + l15) * 64 + quad * 8);
            bf16x8_t wf1 = ldfragW(W2v + (size_t)(mt2 * 16 + l15) * 64 + 32 + quad * 8);
            float4 bv = *(const float4*)(b2v + mt2 * 16 + quad * 4);
            const float* bvp = (const float*)&bv;
            f32x4_t aA = {0.f, 0.f, 0.f, 0.f}, aB = {0.f, 0.f, 0.f, 0.f};
            aA = mfma16(wf0, hdA[0], aA); aA = mfma16(wf1, hdA[1], aA);
            aB = mfma16(wf0, hdB[0], aB); aB = mfma16(wf1, hdB[1], aB);
            float4 oA, oB;
            oA.x = aA[0] + bvp[0]; oA.y = aA[1] + bvp[1]; oA.z = aA[2] + bvp[2]; oA.w = aA[3] + bvp[3];
            oB.x = aB[0] + bvp[0]; oB.y = aB[1] + bvp[1]; oB.z = aB[2] + bvp[2]; oB.w = aB[3] + bvp[3];
            *(float4*)(outp + (size_t)(rbase + l15) * 3072 + mt2 * 16 + quad * 4) = oA;
            *(float4*)(outp + (size_t)(rbase + 16 + l15) * 3072 + mt2 * 16 + quad * 4) = oB;
        }
    }
}

extern "C" void kernel_launch(void* const* d_in, const int* in_sizes, int n_in,
                              void* d_out, int out_size, void* d_ws, size_t ws_size,
                              hipStream_t stream) {
    // setup_inputs order: 0:x(unused) 1:yl 2:yh 3:W_ode 4:b_ode 5:W_ih0 6:W_hh0
    // 7:b_ih0 8:b_hh0 9:W_ih1 10:W_hh1 11:b_ih1 12:b_hh1 13:W1 14:b1 15:W2 16:b2
    const float* yl   = (const float*)d_in[1];
    const float* yh   = (const float*)d_in[2];
    const float* Wode = (const float*)d_in[3];
    const float* bode = (const float*)d_in[4];
    const float* Wih0 = (const float*)d_in[5];
    const float* Whh0 = (const float*)d_in[6];
    const float* bih0 = (const float*)d_in[7];
    const float* bhh0 = (const float*)d_in[8];
    const float* Wih1 = (const float*)d_in[9];
    const float* Whh1 = (const float*)d_in[10];
    const float* bih1 = (const float*)d_in[11];
    const float* bhh1 = (const float*)d_in[12];
    const float* W1v  = (const float*)d_in[13];
    const float* b1v  = (const float*)d_in[14];
    const float* W2v  = (const float*)d_in[15];
    const float* b2v  = (const float*)d_in[16];
    float* outp = (float*)d_out;

    // ws carve: yTraj 25.17 MB | h1Traj 25.17 MB | gi0 75.5 MB | gi1 75.5 MB
    char* wsb = (char*)d_ws;
    unsigned short* yTraj  = (unsigned short*)(wsb);
    unsigned short* h1Traj = (unsigned short*)(wsb + 25165824);
    uint2* gi0 = (uint2*)(wsb + 2 * 25165824);
    uint2* gi1 = (uint2*)(wsb + 2 * 25165824 + 75497472);

    k_ode<<<dim3(32), dim3(512), 0, stream>>>(yl, yh, Wode, bode, yTraj);
    k_gates<<<dim3(96 * 64), dim3(512), 0, stream>>>(Wih0, yTraj, gi0);
    k_gru<<<dim3(32), dim3(512), 0, stream>>>(Whh0, bih0, bhh0, gi0, h1Traj,
                                              W1v, b1v, W2v, b2v, outp, 0);
    k_gates<<<dim3(96 * 64), dim3(512), 0, stream>>>(Wih1, h1Traj, gi1);
    k_gru<<<dim3(32), dim3(512), 0, stream>>>(Whh1, bih1, bhh1, gi1, nullptr,
                                              W1v, b1v, W2v, b2v, outp, 1);
}

// Round 7
// 798.210 us; speedup vs baseline: 2.9449x; 2.9449x over previous
//
#include <hip/hip_runtime.h>
#include <hip/hip_bf16.h>
#include <math.h>

#define TPTS 96
#define CTOT 128
#define LDP 134   // LDS row pitch u16: <=2-way banks (verified R4: conflicts ~0)

typedef __bf16 bf16x8_t __attribute__((ext_vector_type(8)));
typedef float f32x4_t __attribute__((ext_vector_type(4)));
typedef unsigned short us8_t __attribute__((ext_vector_type(8)));

__device__ __forceinline__ unsigned short f2b(float f) {
    union { float f; unsigned int i; } v; v.f = f;
    unsigned int r = v.i + 0x7fffu + ((v.i >> 16) & 1u);
    return (unsigned short)(r >> 16);
}
__device__ __forceinline__ unsigned int packbf2(float a, float b) {
    return (unsigned int)f2b(a) | ((unsigned int)f2b(b) << 16);
}
__device__ __forceinline__ uint2 pack4(float v0, float v1, float v2, float v3) {
    uint2 w; w.x = packbf2(v0, v1); w.y = packbf2(v2, v3); return w;
}
__device__ __forceinline__ f32x4_t mfma16(bf16x8_t a, bf16x8_t b, f32x4_t c) {
    return __builtin_amdgcn_mfma_f32_16x16x32_bf16(a, b, c, 0, 0, 0);
}
__device__ __forceinline__ bf16x8_t ldfrag(const unsigned short* p) {
    us8_t v = *(const us8_t*)p;
    return __builtin_bit_cast(bf16x8_t, v);
}
__device__ __forceinline__ bf16x8_t ldfragW(const float* p) {
    float4 a = *(const float4*)p;
    float4 b = *(const float4*)(p + 4);
    bf16x8_t r;
    r[0] = __builtin_bit_cast(__bf16, f2b(a.x)); r[1] = __builtin_bit_cast(__bf16, f2b(a.y));
    r[2] = __builtin_bit_cast(__bf16, f2b(a.z)); r[3] = __builtin_bit_cast(__bf16, f2b(a.w));
    r[4] = __builtin_bit_cast(__bf16, f2b(b.x)); r[5] = __builtin_bit_cast(__bf16, f2b(b.y));
    r[6] = __builtin_bit_cast(__bf16, f2b(b.z)); r[7] = __builtin_bit_cast(__bf16, f2b(b.w));
    return r;
}
__device__ __forceinline__ float tanh2(float x) {   // finite inputs only
    float e = __expf(x + x);
    return 1.f - __fdividef(2.f, e + 1.f);
}
__device__ __forceinline__ float sigm(float x) {
    return __fdividef(1.f, 1.f + __expf(-x));
}

// cross-block handoff: producer releases flag AFTER __syncthreads (all stores
// vmcnt-drained); consumer tid0 spins with agent-acquire (buffer_inv covers the
// whole CU L1 / XCD L2, killing stale 0xAA-poison lines), then block barrier.
__device__ __forceinline__ void waitflag(unsigned int* f, unsigned int want) {
    if (threadIdx.x == 0) {
        int guard = 0;
        while (__hip_atomic_load(f, __ATOMIC_ACQUIRE, __HIP_MEMORY_SCOPE_AGENT) != want) {
            __builtin_amdgcn_s_sleep(2);
            if (++guard > (1 << 21)) break;   // hang-proof: degrade, don't wedge
        }
    }
    __syncthreads();
}
__device__ __forceinline__ void setflag(unsigned int* f, unsigned int val) {
    if (threadIdx.x == 0)
        __hip_atomic_store(f, val, __ATOMIC_RELEASE, __HIP_MEMORY_SCOPE_AGENT);
}

// 192 blocks x 512 thr: role = blockIdx>>6 (0:ODE producer, 1:GRU0, 2:GRU1+head).
// Each role-c block owns rows [16c,16c+16). ODE critical path = 570 stages; GRU
// consumers run concurrently on other CUs, lagging one step behind their feed.
__global__ void __launch_bounds__(512, 2)
ode_forecaster(const float* __restrict__ yl,
               const float* __restrict__ yh,
               const float* __restrict__ Wode,
               const float* __restrict__ bode,
               const float* __restrict__ Wih0,
               const float* __restrict__ Whh0,
               const float* __restrict__ bih0,
               const float* __restrict__ bhh0,
               const float* __restrict__ Wih1,
               const float* __restrict__ Whh1,
               const float* __restrict__ bih1,
               const float* __restrict__ bhh1,
               const float* __restrict__ W1v,
               const float* __restrict__ b1v,
               const float* __restrict__ W2v,
               const float* __restrict__ b2v,
               float* __restrict__ outp,
               char* __restrict__ wsb)
{
    const int role = blockIdx.x >> 6;
    const int c    = blockIdx.x & 63;
    const int tid  = threadIdx.x, lane = tid & 63, wv = tid >> 6;
    const int l15  = lane & 15, quad = lane >> 4;
    const int fbase = wv * 16 + quad * 4;
    const int rbase = c * 16;

    __shared__ __align__(16) unsigned short zbuf[2][16][LDP];
    __shared__ __align__(16) unsigned short hidbuf[16][72];

    unsigned short* yTraj  = (unsigned short*)(wsb);
    unsigned short* h1Traj = (unsigned short*)(wsb + 0x2000000);
    unsigned int*   yflag  = (unsigned int*)(wsb + 0x4000000);
    unsigned int*   h1flag = (unsigned int*)(wsb + 0x4010000);
#define YMAGIC(t)  (0x5E000000u + (unsigned)(t))
#define H1MAGIC(t) (0x6E000000u + (unsigned)(t))

    if (role == 0) {
        // ================= ODE producer (the serial critical path) ===========
        bf16x8_t wode[4];
#pragma unroll
        for (int kt = 0; kt < 4; ++kt)
            wode[kt] = ldfragW(Wode + (wv * 16 + l15) * CTOT + kt * 32 + quad * 8);
        float bo[4];
        {
            float4 b4 = *(const float4*)(bode + fbase);
            bo[0] = b4.x; bo[1] = b4.y; bo[2] = b4.z; bo[3] = b4.w;
        }
        float y[4];
        {
            int row = rbase + l15;
#pragma unroll
            for (int i = 0; i < 4; ++i) {
                int f = fbase + i;
                y[i] = (f < 32) ? yl[row * 32 + f] : yh[row * 96 + (f - 32)];
            }
            uint2 pk = pack4(y[0], y[1], y[2], y[3]);
            *(uint2*)&zbuf[0][l15][fbase] = pk;
            *(uint2*)(yTraj + ((size_t)row) * CTOT + fbase) = pk;
        }
        __syncthreads();
        setflag(&yflag[c * 128 + 0], YMAGIC(0));

        // dt-folded Dormand-Prince coefficients
        const float dt = 1.0f / 95.0f;
        const float d10 = dt * 0.2f;
        const float d20 = dt * (3.f/40.f),  d21 = dt * (9.f/40.f);
        const float d30 = dt * (44.f/45.f), d31 = dt * (-56.f/15.f), d32 = dt * (32.f/9.f);
        const float d40 = dt * (19372.f/6561.f), d41 = dt * (-25360.f/2187.f),
                    d42 = dt * (64448.f/6561.f), d43 = dt * (-212.f/729.f);
        const float d50 = dt * (9017.f/3168.f), d51 = dt * (-355.f/33.f),
                    d52 = dt * (46732.f/5247.f), d53 = dt * (49.f/176.f),
                    d54 = dt * (-5103.f/18656.f);
        const float e0 = dt * (35.f/384.f), e2 = dt * (500.f/1113.f), e3 = dt * (125.f/192.f),
                    e4 = dt * (-2187.f/6784.f), e5 = dt * (11.f/84.f);

        int p = 0;
        float kr[6][4];
#pragma unroll 1
        for (int t = 0; t < 95; ++t) {
#pragma unroll
            for (int s = 0; s < 6; ++s) {
                bf16x8_t bf[4];
#pragma unroll
                for (int kt = 0; kt < 4; ++kt)
                    bf[kt] = ldfrag(&zbuf[p][l15][kt * 32 + quad * 8]);
                // 2+2 split: halves the dependent MFMA chain depth
                f32x4_t a0 = {0.f, 0.f, 0.f, 0.f}, a1 = {0.f, 0.f, 0.f, 0.f};
                a0 = mfma16(wode[0], bf[0], a0);
                a1 = mfma16(wode[1], bf[1], a1);
                a0 = mfma16(wode[2], bf[2], a0);
                a1 = mfma16(wode[3], bf[3], a1);
                f32x4_t acc = a0 + a1;
#pragma unroll
                for (int i = 0; i < 4; ++i) kr[s][i] = tanh2(acc[i] + bo[i]);

                if (s < 5) {
                    float z[4];
#pragma unroll
                    for (int i = 0; i < 4; ++i) {
                        float zv;
                        if (s == 0)      zv = y[i] + d10 * kr[0][i];
                        else if (s == 1) zv = y[i] + d20 * kr[0][i] + d21 * kr[1][i];
                        else if (s == 2) zv = y[i] + d30 * kr[0][i] + d31 * kr[1][i] + d32 * kr[2][i];
                        else if (s == 3) zv = y[i] + d40 * kr[0][i] + d41 * kr[1][i]
                                             + d42 * kr[2][i] + d43 * kr[3][i];
                        else             zv = y[i] + d50 * kr[0][i] + d51 * kr[1][i]
                                             + d52 * kr[2][i] + d53 * kr[3][i] + d54 * kr[4][i];
                        z[i] = zv;
                    }
                    *(uint2*)&zbuf[p ^ 1][l15][fbase] = pack4(z[0], z[1], z[2], z[3]);
                } else {
#pragma unroll
                    for (int i = 0; i < 4; ++i)
                        y[i] += e0*kr[0][i] + e2*kr[2][i] + e3*kr[3][i] + e4*kr[4][i] + e5*kr[5][i];
                    uint2 pk = pack4(y[0], y[1], y[2], y[3]);
                    *(uint2*)&zbuf[p ^ 1][l15][fbase] = pk;
                    *(uint2*)(yTraj + ((size_t)(t + 1) * 1024 + rbase + l15) * CTOT + fbase) = pk;
                }
                __syncthreads();
                p ^= 1;
                if (s == 5) setflag(&yflag[c * 128 + t + 1], YMAGIC(t + 1));
            }
        }
        return;
    }

    // ==================== GRU consumer roles ==================================
    const float* Wih = (role == 1) ? Wih0 : Wih1;
    const float* Whh = (role == 1) ? Whh0 : Whh1;
    const float* bih = (role == 1) ? bih0 : bih1;
    const float* bhh = (role == 1) ? bhh0 : bhh1;
    const unsigned short* src = (role == 1) ? yTraj : h1Traj;
    unsigned int* sflag = (role == 1) ? yflag : h1flag;

    bf16x8_t wih[3][4], whh[3][4];
#pragma unroll
    for (int g = 0; g < 3; ++g)
#pragma unroll
        for (int kt = 0; kt < 4; ++kt) {
            wih[g][kt] = ldfragW(Wih + (size_t)(g * 128 + wv * 16 + l15) * CTOT + kt * 32 + quad * 8);
            whh[g][kt] = ldfragW(Whh + (size_t)(g * 128 + wv * 16 + l15) * CTOT + kt * 32 + quad * 8);
        }
    float br[4], bz[4], bin_[4], bhn[4];
    {
        float4 a0 = *(const float4*)(bih + 0 * 128 + fbase);
        float4 b0 = *(const float4*)(bhh + 0 * 128 + fbase);
        float4 a1 = *(const float4*)(bih + 1 * 128 + fbase);
        float4 b1 = *(const float4*)(bhh + 1 * 128 + fbase);
        float4 a2 = *(const float4*)(bih + 2 * 128 + fbase);
        float4 b2 = *(const float4*)(bhh + 2 * 128 + fbase);
        br[0] = a0.x + b0.x; br[1] = a0.y + b0.y; br[2] = a0.z + b0.z; br[3] = a0.w + b0.w;
        bz[0] = a1.x + b1.x; bz[1] = a1.y + b1.y; bz[2] = a1.z + b1.z; bz[3] = a1.w + b1.w;
        bin_[0] = a2.x; bin_[1] = a2.y; bin_[2] = a2.z; bin_[3] = a2.w;
        bhn[0] = b2.x; bhn[1] = b2.y; bhn[2] = b2.z; bhn[3] = b2.w;
    }

    float h[4] = {0.f, 0.f, 0.f, 0.f};
    *(uint2*)&zbuf[0][l15][fbase] = pack4(0.f, 0.f, 0.f, 0.f);
    int p = 0;
    __syncthreads();

#pragma unroll 1
    for (int t = 0; t < TPTS; ++t) {
        waitflag(&sflag[c * 128 + t], (role == 1) ? YMAGIC(t) : H1MAGIC(t));
        const unsigned short* xp = src + ((size_t)t * 1024 + rbase + l15) * CTOT;
        bf16x8_t ax[4], ah[4];
#pragma unroll
        for (int kt = 0; kt < 4; ++kt) {
            ax[kt] = ldfrag(xp + kt * 32 + quad * 8);
            ah[kt] = ldfrag(&zbuf[p][l15][kt * 32 + quad * 8]);
        }
        f32x4_t gx[3], gh[3];
#pragma unroll
        for (int g = 0; g < 3; ++g) {
            gx[g] = (f32x4_t){0.f, 0.f, 0.f, 0.f};
            gh[g] = (f32x4_t){0.f, 0.f, 0.f, 0.f};
        }
#pragma unroll
        for (int kt = 0; kt < 4; ++kt) {
            gx[0] = mfma16(wih[0][kt], ax[kt], gx[0]);
            gx[1] = mfma16(wih[1][kt], ax[kt], gx[1]);
            gx[2] = mfma16(wih[2][kt], ax[kt], gx[2]);
            gh[0] = mfma16(whh[0][kt], ah[kt], gh[0]);
            gh[1] = mfma16(whh[1][kt], ah[kt], gh[1]);
            gh[2] = mfma16(whh[2][kt], ah[kt], gh[2]);
        }
#pragma unroll
        for (int i = 0; i < 4; ++i) {
            float rr = sigm(gx[0][i] + gh[0][i] + br[i]);
            float zz = sigm(gx[1][i] + gh[1][i] + bz[i]);
            float nn = tanh2((gx[2][i] + bin_[i]) + rr * (gh[2][i] + bhn[i]));
            h[i] = nn + zz * (h[i] - nn);
        }
        uint2 pk = pack4(h[0], h[1], h[2], h[3]);
        *(uint2*)&zbuf[p ^ 1][l15][fbase] = pk;
        if (role == 1)
            *(uint2*)(h1Traj + ((size_t)t * 1024 + rbase + l15) * CTOT + fbase) = pk;
        __syncthreads();
        if (role == 1) setflag(&h1flag[c * 128 + t], H1MAGIC(t));
        p ^= 1;
    }
    if (role == 1) return;

    // ==================== MLP head (role 2) ===================================
    if (wv < 4) {
        bf16x8_t wf[4], hf[4];
#pragma unroll
        for (int kt = 0; kt < 4; ++kt) {
            wf[kt] = ldfragW(W1v + (size_t)(wv * 16 + l15) * CTOT + kt * 32 + quad * 8);
            hf[kt] = ldfrag(&zbuf[p][l15][kt * 32 + quad * 8]);
        }
        f32x4_t acc = {0.f, 0.f, 0.f, 0.f};
#pragma unroll
        for (int kt = 0; kt < 4; ++kt) acc = mfma16(wf[kt], hf[kt], acc);
        float4 bb = *(const float4*)(b1v + wv * 16 + quad * 4);
        const float* bbp = (const float*)&bb;
        float gl[4];
#pragma unroll
        for (int i = 0; i < 4; ++i) {
            float x = acc[i] + bbp[i];
            gl[i] = 0.5f * x * (1.0f + erff(x * 0.70710678118654752f));
        }
        *(uint2*)&hidbuf[l15][wv * 16 + quad * 4] = pack4(gl[0], gl[1], gl[2], gl[3]);
    }
    __syncthreads();

    bf16x8_t ahid[2];
#pragma unroll
    for (int kt = 0; kt < 2; ++kt)
        ahid[kt] = ldfrag(&hidbuf[l15][kt * 32 + quad * 8]);
#pragma unroll 1
    for (int j = 0; j < 24; ++j) {
        int mt2 = wv * 24 + j;
        bf16x8_t wf0 = ldfragW(W2v + (size_t)(mt2 * 16 + l15) * 64 + quad * 8);
        bf16x8_t wf1 = ldfragW(W2v + (size_t)(mt2 * 16 + l15) * 64 + 32 + quad * 8);
        float4 bv = *(const float4*)(b2v + mt2 * 16 + quad * 4);
        const float* bvp = (const float*)&bv;
        f32x4_t acc = {0.f, 0.f, 0.f, 0.f};
        acc = mfma16(wf0, ahid[0], acc);
        acc = mfma16(wf1, ahid[1], acc);
        float4 o;
        o.x = acc[0] + bvp[0]; o.y = acc[1] + bvp[1];
        o.z = acc[2] + bvp[2]; o.w = acc[3] + bvp[3];
        *(float4*)(outp + (size_t)(rbase + l15) * 3072 + mt2 * 16 + quad * 4) = o;
    }
#undef YMAGIC
#undef H1MAGIC
}

extern "C" void kernel_launch(void* const* d_in, const int* in_sizes, int n_in,
                              void* d_out, int out_size, void* d_ws, size_t ws_size,
                              hipStream_t stream) {
    // setup_inputs order: 0:x(unused) 1:yl 2:yh 3:W_ode 4:b_ode 5:W_ih0 6:W_hh0
    // 7:b_ih0 8:b_hh0 9:W_ih1 10:W_hh1 11:b_ih1 12:b_hh1 13:W1 14:b1 15:W2 16:b2
    const float* yl   = (const float*)d_in[1];
    const float* yh   = (const float*)d_in[2];
    const float* Wode = (const float*)d_in[3];
    const float* bode = (const float*)d_in[4];
    const float* Wih0 = (const float*)d_in[5];
    const float* Whh0 = (const float*)d_in[6];
    const float* bih0 = (const float*)d_in[7];
    const float* bhh0 = (const float*)d_in[8];
    const float* Wih1 = (const float*)d_in[9];
    const float* Whh1 = (const float*)d_in[10];
    const float* bih1 = (const float*)d_in[11];
    const float* bhh1 = (const float*)d_in[12];
    const float* W1v  = (const float*)d_in[13];
    const float* b1v  = (const float*)d_in[14];
    const float* W2v  = (const float*)d_in[15];
    const float* b2v  = (const float*)d_in[16];

    ode_forecaster<<<dim3(192), dim3(512), 0, stream>>>(
        yl, yh, Wode, bode, Wih0, Whh0, bih0, bhh0,
        Wih1, Whh1, bih1, bhh1, W1v, b1v, W2v, b2v,
        (float*)d_out, (char*)d_ws);
}